// Round 2
// baseline (169.957 us; speedup 1.0000x reference)
//
#include <hip/hip_runtime.h>
#include <math.h>

// Problem constants (reference: N=16384, D=2, H=128, fp32)
#define N_ROWS 16384
#define HDIM   128
#define NH     (N_ROWS * HDIM)   // 2097152 floats per [N,H] output
#define NH4    (NH / 4)          // 524288 float4
#define B1     512               // blocks for kernel 1

// Workspace layout (in floats)
#define WS_SY_PART 0                         // B1*128 : per-block column-sum partials of bi_dec
#define WS_YN      (B1 * 128)                // B1     : per-block partials of sum ||y||^2
#define WS_XN      (WS_YN + B1)              // N_ROWS : per-row ||x_i||^2
#define WS_DGR     (WS_XN + N_ROWS)          // N_ROWS : per-row diag_i = ||x_i - y_i||^2

// K1: elementwise bi_enc/bi_dec + per-row stats + block partial reductions.
// bi_enc[i][h] = enc[i*256 + h] + enc[i*256 + 128 + h]; same for dec.
// float4 index v in [0, NH4): row = v/32, h4 = v%32. Lanes 0..31 of a wave
// hold one full row (consecutive v), so width-32 shfl trees give per-row sums.
__global__ __launch_bounds__(256) void k1_elementwise(
    const float4* __restrict__ enc, const float4* __restrict__ dec,
    float* __restrict__ outf, float* __restrict__ ws)
{
    float4* out4 = reinterpret_cast<float4*>(outf);
    const int tid  = threadIdx.x;
    const int gid0 = blockIdx.x * 256 + tid;
    const int stride = B1 * 256;          // multiple of 32 -> h4 fixed per thread
    const int h4 = tid & 31;

    float4 asy = make_float4(0.f, 0.f, 0.f, 0.f);
    float ayn = 0.f;

    for (int v = gid0; v < NH4; v += stride) {   // 4 iterations
        const int base = 2 * v - h4;
        float4 e0 = enc[base];
        float4 e1 = enc[base + 32];
        float4 d0 = dec[base];
        float4 d1 = dec[base + 32];
        float4 x = make_float4(e0.x + e1.x, e0.y + e1.y, e0.z + e1.z, e0.w + e1.w);
        float4 y = make_float4(d0.x + d1.x, d0.y + d1.y, d0.z + d1.z, d0.w + d1.w);
        out4[v] = x;                 // output 0: bi_enc
        out4[NH4 + v] = x;           // output 1: bi_enc (duplicate)
        out4[2 * NH4 + v] = y;       // output 2: bi_dec

        asy.x += y.x; asy.y += y.y; asy.z += y.z; asy.w += y.w;
        ayn += y.x * y.x + y.y * y.y + y.z * y.z + y.w * y.w;

        // per-row stats via width-32 shuffle tree (lanes 0..31 = one row)
        float xn = x.x * x.x + x.y * x.y + x.z * x.z + x.w * x.w;
        float fx = x.x - y.x, fy = x.y - y.y, fz = x.z - y.z, fw = x.w - y.w;
        float dg = fx * fx + fy * fy + fz * fz + fw * fw;
        #pragma unroll
        for (int off = 16; off > 0; off >>= 1) {
            xn += __shfl_down(xn, off, 32);
            dg += __shfl_down(dg, off, 32);
        }
        if (h4 == 0) {
            const int row = v >> 5;
            ws[WS_XN + row]  = xn;
            ws[WS_DGR + row] = dg;
        }
    }

    __shared__ float4 ssy[256];
    __shared__ float s1[256];
    ssy[tid] = asy; s1[tid] = ayn;
    __syncthreads();
    for (int off = 128; off > 0; off >>= 1) {
        if (tid < off) s1[tid] += s1[tid + off];
        __syncthreads();
    }
    if (tid < 32) {
        float4 t = ssy[tid];
        #pragma unroll
        for (int k = 1; k < 8; ++k) {
            float4 u = ssy[tid + 32 * k];
            t.x += u.x; t.y += u.y; t.z += u.z; t.w += u.w;
        }
        reinterpret_cast<float4*>(ws + WS_SY_PART)[blockIdx.x * 32 + tid] = t;
    }
    if (tid == 0) ws[WS_YN + blockIdx.x] = s1[0];
}

// K2 (single block): finalize everything.
//  - S_y[128] and sum||y||^2 from block partials
//  - diagonal_loss = -sum(diag_i)/N  (fp64 accumulate)
//  - nce: row_loss_i = 5 - (N*xn_i + sumyn - 2*x_i.S_y) + 10*diag_i.
//    Cauchy-Schwarz: x_i.S_y <= sqrt(xn_i * ||S_y||^2), so
//    row_loss_i <= 5 - N*xn_i - sumyn + 2*sqrt(xn_i*||S_y||^2) + 10*diag_i.
//    If that bound < -1000 (always, for this data: ~-8.4e6) the clamp gives 0
//    exactly. Exact per-row fallback (dot with S_y) for the never-taken case.
__global__ __launch_bounds__(256) void k2_finalize(
    float* __restrict__ ws, float* __restrict__ outf)
{
    const int tid = threadIdx.x;
    __shared__ float sy[128];
    __shared__ float tmp[256];
    __shared__ double red[256];
    __shared__ float s_ss2, s_sumyn;

    // 1. S_y: thread (col = tid&127, half = tid>>7) sums 256 block partials
    {
        const int col = tid & 127, half = tid >> 7;
        float s = 0.f;
        for (int b = half * 256; b < half * 256 + 256; ++b)
            s += ws[WS_SY_PART + b * 128 + col];
        tmp[tid] = s;
        __syncthreads();
        if (tid < 128) sy[tid] = tmp[tid] + tmp[tid + 128];
        __syncthreads();
    }

    // 2. ||S_y||^2 (fp32) and sumyn (fp64 accumulate of 512 partials)
    {
        tmp[tid] = (tid < 128) ? sy[tid] * sy[tid] : 0.f;
        double a = 0.0;
        for (int i = tid; i < B1; i += 256) a += (double)ws[WS_YN + i];
        red[tid] = a;
        __syncthreads();
        for (int off = 128; off > 0; off >>= 1) {
            if (tid < off) { tmp[tid] += tmp[tid + off]; red[tid] += red[tid + off]; }
            __syncthreads();
        }
        if (tid == 0) { s_ss2 = tmp[0]; s_sumyn = (float)red[0]; }
        __syncthreads();
    }

    const float ss2   = s_ss2;
    const float sumyn = s_sumyn;

    // 3. Row scan: diag sum (fp64) + nce via bound (exact fallback never fires)
    double dsum = 0.0;
    float nce = 0.f;
    for (int i = tid; i < N_ROWS; i += 256) {
        const float xn = ws[WS_XN + i];
        const float dg = ws[WS_DGR + i];
        dsum += (double)dg;
        const float bound = 5.f - (float)N_ROWS * xn - sumyn
                            + 2.f * sqrtf(xn * ss2) + 10.f * dg;
        if (bound > -1000.f) {   // measure-zero path: exact row_loss
            const float* xrow = outf + i * HDIM;   // bi_enc row
            float xs = 0.f;
            for (int h = 0; h < HDIM; ++h) xs += xrow[h] * sy[h];
            const float rowsum = (float)N_ROWS * xn + sumyn - 2.f * xs;
            const float rl = 5.f - rowsum + 10.f * dg;
            nce += fmaxf(rl, 0.f);
        }
    }
    red[tid] = dsum; tmp[tid] = nce;
    __syncthreads();
    for (int off = 128; off > 0; off >>= 1) {
        if (tid < off) { red[tid] += red[tid + off]; tmp[tid] += tmp[tid + off]; }
        __syncthreads();
    }
    if (tid == 0) {
        outf[3 * NH]     = tmp[0];                                  // nce_loss
        outf[3 * NH + 1] = (float)(-red[0] / (double)N_ROWS);       // diagonal_loss
    }
}

extern "C" void kernel_launch(void* const* d_in, const int* in_sizes, int n_in,
                              void* d_out, int out_size, void* d_ws, size_t ws_size,
                              hipStream_t stream) {
    const float4* enc = (const float4*)d_in[0];   // [16384, 2, 128] fp32
    const float4* dec = (const float4*)d_in[1];   // [16384, 2, 128] fp32
    float* out = (float*)d_out;                   // 3*NH + 2 floats
    float* ws  = (float*)d_ws;

    k1_elementwise<<<B1, 256, 0, stream>>>(enc, dec, out, ws);
    k2_finalize<<<1, 256, 0, stream>>>(ws, out);
}

// Round 3
// 145.505 us; speedup vs baseline: 1.1680x; 1.1680x over previous
//
#include <hip/hip_runtime.h>
#include <math.h>

// Problem constants (reference: N=16384, D=2, H=128, fp32)
#define N_ROWS 16384
#define HDIM   128
#define NH     (N_ROWS * HDIM)   // 2097152 floats per [N,H] output
#define NH4    (NH / 4)          // 524288 float4
#define B1     512               // blocks for kernel 1

// Workspace accumulators (zeroed by hipMemsetAsync before k1):
//   double ws[0] : sum ||y_j||^2        (fp64 atomic)
//   double ws[1] : sum_i ||x_i-y_i||^2  (fp64 atomic)  -> diagonal_loss
//   int    at byte 16 : max_i dg_i as float bits (all dg>=0, int order == float order)
//   float  at byte 32 .. 32+512 : S_y[128] column sums (fp32 atomics)
#define WS_DGMAX_OFF 4   // in floats
#define WS_SY_OFF    8   // in floats

// K1: streaming pass. bi_enc[i][h] = enc[i*256+h] + enc[i*256+128+h]; same dec.
// float4 index v in [0,NH4): row = v>>5, h4 = v&31; enc float4 addr = 2v-h4 (+32 dir1).
// Lanes 0..31 / 32..63 of a wave each hold one full row per iteration, so a
// width-32 butterfly gives every lane the row's diag dg; per-thread running max.
__global__ __launch_bounds__(256) void k1_stream(
    const float4* __restrict__ enc, const float4* __restrict__ dec,
    float* __restrict__ outf, float* __restrict__ ws)
{
    float4* out4 = reinterpret_cast<float4*>(outf);
    double* wsd  = reinterpret_cast<double*>(ws);
    int*    wdg  = reinterpret_cast<int*>(ws + WS_DGMAX_OFF);
    float*  wsy  = ws + WS_SY_OFF;

    const int tid  = threadIdx.x;
    const int gid0 = blockIdx.x * 256 + tid;
    const int stride = B1 * 256;          // multiple of 32 -> h4 fixed per thread
    const int h4 = tid & 31;

    float4 asy = make_float4(0.f, 0.f, 0.f, 0.f);
    float ayn = 0.f, adg = 0.f, dgmx = 0.f;

    for (int v = gid0; v < NH4; v += stride) {   // 4 iterations
        const int base = 2 * v - h4;
        float4 e0 = enc[base];
        float4 e1 = enc[base + 32];
        float4 d0 = dec[base];
        float4 d1 = dec[base + 32];
        float4 x = make_float4(e0.x + e1.x, e0.y + e1.y, e0.z + e1.z, e0.w + e1.w);
        float4 y = make_float4(d0.x + d1.x, d0.y + d1.y, d0.z + d1.z, d0.w + d1.w);
        out4[v] = x;                 // output 0: bi_enc
        out4[NH4 + v] = x;           // output 1: bi_enc (duplicate)
        out4[2 * NH4 + v] = y;       // output 2: bi_dec

        asy.x += y.x; asy.y += y.y; asy.z += y.z; asy.w += y.w;
        ayn += y.x * y.x + y.y * y.y + y.z * y.z + y.w * y.w;

        float fx = x.x - y.x, fy = x.y - y.y, fz = x.z - y.z, fw = x.w - y.w;
        float dg = fx * fx + fy * fy + fz * fz + fw * fw;
        adg += dg;
        // full-row dg on every lane via width-32 butterfly
        #pragma unroll
        for (int m = 16; m > 0; m >>= 1) dg += __shfl_xor(dg, m, 32);
        dgmx = fmaxf(dgmx, dg);
    }

    __shared__ float4 ssy[256];
    __shared__ float s_yn[256], s_dg[256], s_mx[256];
    ssy[tid] = asy; s_yn[tid] = ayn; s_dg[tid] = adg; s_mx[tid] = dgmx;
    __syncthreads();
    for (int off = 128; off > 0; off >>= 1) {
        if (tid < off) {
            s_yn[tid] += s_yn[tid + off];
            s_dg[tid] += s_dg[tid + off];
            s_mx[tid]  = fmaxf(s_mx[tid], s_mx[tid + off]);
        }
        __syncthreads();
    }
    if (tid < 32) {   // column sums: thread t owns columns 4t..4t+3
        float4 t = ssy[tid];
        #pragma unroll
        for (int k = 1; k < 8; ++k) {
            float4 u = ssy[tid + 32 * k];
            t.x += u.x; t.y += u.y; t.z += u.z; t.w += u.w;
        }
        atomicAdd(wsy + 4 * tid + 0, t.x);
        atomicAdd(wsy + 4 * tid + 1, t.y);
        atomicAdd(wsy + 4 * tid + 2, t.z);
        atomicAdd(wsy + 4 * tid + 3, t.w);
    }
    if (tid == 0) {
        atomicAdd(wsd + 0, (double)s_yn[0]);
        atomicAdd(wsd + 1, (double)s_dg[0]);
        atomicMax(wdg, __float_as_int(s_mx[0]));   // dg >= 0: int order == float order
    }
}

// K2 (1 tiny block): global bound proves nce == 0, write scalars.
// row_loss_i = 5 - sum_j dist_cl[i,j] + 10*dg_i  with dist_cl >= dist_exact, so
// row_loss_i <= 5 - N*xn_i - sumyn + 2*sqrt(xn_i*||S_y||^2) + 10*dg_i
//            <= 5 + ||S_y||^2/N - sumyn + 10*max_dg   (max over xn_i, Cauchy-Schwarz).
// For this data: ~ 5 + 128 - 4.2e6 + 4e3 << 0  ->  every clamped row_loss is 0.
// Exact O(N^2 H) fallback included for full generality (never taken).
__global__ __launch_bounds__(256) void k2_finalize(
    const float* __restrict__ ws, float* __restrict__ outf)
{
    const int tid = threadIdx.x;
    const double* wsd = reinterpret_cast<const double*>(ws);
    const float sumyn = (float)wsd[0];
    const double dsum = wsd[1];
    const float dgmax = __int_as_float(reinterpret_cast<const int*>(ws + WS_DGMAX_OFF)[0]);
    const float* wsy  = ws + WS_SY_OFF;

    __shared__ float red[256];
    red[tid] = (tid < 128) ? wsy[tid] * wsy[tid] : 0.f;
    __syncthreads();
    for (int off = 128; off > 0; off >>= 1) {
        if (tid < off) red[tid] += red[tid + off];
        __syncthreads();
    }
    const float ss2 = red[0];
    __syncthreads();

    const float bound = 5.f + ss2 / (float)N_ROWS - sumyn + 10.f * dgmax;

    if (bound < -1.0e4f) {
        if (tid == 0) {
            outf[3 * NH]     = 0.0f;                              // nce_loss
            outf[3 * NH + 1] = (float)(-dsum / (double)N_ROWS);   // diagonal_loss
        }
        return;
    }

    // ---- exact fallback (unreachable for Gaussian benchmark data) ----
    __shared__ double snce[256];
    const float* X = outf;            // bi_enc
    const float* Y = outf + 2 * NH;   // bi_dec
    double nce = 0.0;
    for (int i = tid; i < N_ROWS; i += 256) {
        const float* xi = X + i * HDIM;
        float xn = 0.f;
        for (int h = 0; h < HDIM; ++h) xn += xi[h] * xi[h];
        double rowsum = 0.0;
        for (int j = 0; j < N_ROWS; ++j) {
            const float* yj = Y + j * HDIM;
            float yn = 0.f, xy = 0.f;
            for (int h = 0; h < HDIM; ++h) { yn += yj[h] * yj[h]; xy += xi[h] * yj[h]; }
            rowsum += (double)fmaxf(xn + yn - 2.f * xy, 0.f);
        }
        const float* yi = Y + i * HDIM;
        float yn = 0.f, xy = 0.f;
        for (int h = 0; h < HDIM; ++h) { yn += yi[h] * yi[h]; xy += xi[h] * yi[h]; }
        const float diag = fmaxf(xn + yn - 2.f * xy, 0.f);
        const double rl = 5.0 - rowsum + 10.0 * (double)diag;
        nce += (rl > 0.0) ? rl : 0.0;
    }
    snce[tid] = nce;
    __syncthreads();
    for (int off = 128; off > 0; off >>= 1) {
        if (tid < off) snce[tid] += snce[tid + off];
        __syncthreads();
    }
    if (tid == 0) {
        outf[3 * NH]     = (float)snce[0];
        outf[3 * NH + 1] = (float)(-dsum / (double)N_ROWS);
    }
}

extern "C" void kernel_launch(void* const* d_in, const int* in_sizes, int n_in,
                              void* d_out, int out_size, void* d_ws, size_t ws_size,
                              hipStream_t stream) {
    const float4* enc = (const float4*)d_in[0];   // [16384, 2, 128] fp32
    const float4* dec = (const float4*)d_in[1];   // [16384, 2, 128] fp32
    float* out = (float*)d_out;                   // 3*NH + 2 floats
    float* ws  = (float*)d_ws;

    hipMemsetAsync(ws, 0, 1024, stream);          // zero accumulators (capture-legal)
    k1_stream<<<B1, 256, 0, stream>>>(enc, dec, out, ws);
    k2_finalize<<<1, 256, 0, stream>>>(ws, out);
}

// Round 4
// 89.601 us; speedup vs baseline: 1.8968x; 1.6239x over previous
//
#include <hip/hip_runtime.h>
#include <math.h>

// Problem constants (reference: N=16384, D=2, H=128, fp32)
#define N_ROWS 16384
#define HDIM   128
#define NH     (N_ROWS * HDIM)   // 2097152 floats per [N,H] output
#define NH4    (NH / 4)          // 524288 float4
#define B1     2048              // k1 blocks: 2048*256 threads = one float4 each

// Workspace layout (float offsets). Everything is written before read; no
// atomics, no zero-init needed.
#define OFF_SY1 0                      // 2048*128 : per-k1-block column sums of bi_dec
#define OFF_YN1 262144                 // 2048     : per-k1-block sum ||y||^2
#define OFF_DG1 264192                 // 2048     : per-k1-block sum (x-y)^2
#define OFF_MX1 266240                 // 2048     : per-k1-block max row diag
#define OFF_SY2 268288                 // 32*128   : k2 folded column sums
#define OFF_YN2 272384                 // 32
#define OFF_MX2 272416                 // 32
#define OFF_DG2 272448                 // 32 doubles (64 floats), 8B-aligned

// K1: pure streaming pass, one float4 of the bi-sum per thread.
// bi[i][h] = in[i*256 + h] + in[i*256 + 128 + h].
// float4 index v: row = v>>5, h4 = v&31; input float4 addr = 2v-h4 (+32 dir1).
// Lanes 0..31 of each half-wave hold one full row -> width-32 butterfly gives
// the row diag on every lane.
__global__ __launch_bounds__(256) void k1_stream(
    const float4* __restrict__ enc, const float4* __restrict__ dec,
    float* __restrict__ outf, float* __restrict__ ws)
{
    float4* out4 = reinterpret_cast<float4*>(outf);
    const int tid = threadIdx.x;
    const int b   = blockIdx.x;
    const int v   = b * 256 + tid;
    const int h4  = tid & 31;
    const int base = 2 * v - h4;

    float4 e0 = enc[base];
    float4 e1 = enc[base + 32];
    float4 d0 = dec[base];
    float4 d1 = dec[base + 32];
    float4 x = make_float4(e0.x + e1.x, e0.y + e1.y, e0.z + e1.z, e0.w + e1.w);
    float4 y = make_float4(d0.x + d1.x, d0.y + d1.y, d0.z + d1.z, d0.w + d1.w);
    out4[v]           = x;   // output 0: bi_enc
    out4[NH4 + v]     = x;   // output 1: bi_enc (duplicate)
    out4[2 * NH4 + v] = y;   // output 2: bi_dec

    const float ayn = y.x * y.x + y.y * y.y + y.z * y.z + y.w * y.w;
    const float fx = x.x - y.x, fy = x.y - y.y, fz = x.z - y.z, fw = x.w - y.w;
    const float dg4 = fx * fx + fy * fy + fz * fz + fw * fw;
    float dgrow = dg4;
    #pragma unroll
    for (int m = 16; m > 0; m >>= 1) dgrow += __shfl_xor(dgrow, m, 32);

    __shared__ float4 ssy[256];
    __shared__ float s_yn[256], s_dg[256], s_mx[256];
    ssy[tid] = y; s_yn[tid] = ayn; s_dg[tid] = dg4; s_mx[tid] = dgrow;
    __syncthreads();
    for (int off = 128; off > 0; off >>= 1) {
        if (tid < off) {
            s_yn[tid] += s_yn[tid + off];
            s_dg[tid] += s_dg[tid + off];
            s_mx[tid]  = fmaxf(s_mx[tid], s_mx[tid + off]);
        }
        __syncthreads();
    }
    if (tid < 32) {   // column partial: sum y over the block's 8 rows
        float4 t = ssy[tid];
        #pragma unroll
        for (int k = 1; k < 8; ++k) {
            float4 u = ssy[tid + 32 * k];
            t.x += u.x; t.y += u.y; t.z += u.z; t.w += u.w;
        }
        reinterpret_cast<float4*>(ws + OFF_SY1)[b * 32 + tid] = t;
    }
    if (tid == 0) {
        ws[OFF_YN1 + b] = s_yn[0];
        ws[OFF_DG1 + b] = s_dg[0];
        ws[OFF_MX1 + b] = s_mx[0];
    }
}

// K2: 32 blocks; block g folds partial rows g*64..g*64+63 into one row.
__global__ __launch_bounds__(256) void k2_fold(float* __restrict__ ws)
{
    const int g = blockIdx.x, tid = threadIdx.x;
    const float4* SY1 = reinterpret_cast<const float4*>(ws + OFF_SY1);
    float4* SY2 = reinterpret_cast<float4*>(ws + OFF_SY2);

    const int col4 = tid & 31, r = tid >> 5;   // 8 row-slices
    float4 a = make_float4(0.f, 0.f, 0.f, 0.f);
    #pragma unroll
    for (int j = 0; j < 8; ++j) {
        float4 u = SY1[(g * 64 + r * 8 + j) * 32 + col4];
        a.x += u.x; a.y += u.y; a.z += u.z; a.w += u.w;
    }
    __shared__ float4 sred[256];
    sred[tid] = a;
    __syncthreads();
    for (int off = 128; off >= 32; off >>= 1) {
        if (tid < off) {
            float4 u = sred[tid + off];
            sred[tid].x += u.x; sred[tid].y += u.y;
            sred[tid].z += u.z; sred[tid].w += u.w;
        }
        __syncthreads();
    }
    if (tid < 32) SY2[g * 32 + tid] = sred[tid];

    __shared__ float syn[64], smx[64];
    __shared__ double sdg[64];
    if (tid < 64) {
        syn[tid] = ws[OFF_YN1 + g * 64 + tid];
        sdg[tid] = (double)ws[OFF_DG1 + g * 64 + tid];
        smx[tid] = ws[OFF_MX1 + g * 64 + tid];
    }
    __syncthreads();
    for (int off = 32; off > 0; off >>= 1) {
        if (tid < off) {
            syn[tid] += syn[tid + off];
            sdg[tid] += sdg[tid + off];
            smx[tid]  = fmaxf(smx[tid], smx[tid + off]);
        }
        __syncthreads();
    }
    if (tid == 0) {
        ws[OFF_YN2 + g] = syn[0];
        ws[OFF_MX2 + g] = smx[0];
        reinterpret_cast<double*>(ws + OFF_DG2)[g] = sdg[0];
    }
}

// K3 (1 tiny block): finalize.
// row_loss_i = 5 - sum_j dist_cl[i,j] + 10*dg_i, dist_cl >= dist_exact, so
// row_loss_i <= 5 - N*xn_i - sumyn + 2*sqrt(xn_i*||S_y||^2) + 10*dg_i
//            <= 5 + ||S_y||^2/N - sumyn + 10*max_dg   (max over xn, C-S).
// Here ~ 5 + 256 - 4.2e6 + ~1e4 << 0  ->  every clamped row_loss is 0 exactly.
// Exact O(N^2 H) fallback kept for full generality (never taken).
__global__ __launch_bounds__(256) void k3_finalize(
    const float* __restrict__ ws, float* __restrict__ outf)
{
    const int tid = threadIdx.x;
    __shared__ float red[256];
    __shared__ float syn[32], smx[32];
    __shared__ double sdg[32];

    float s = 0.f;
    if (tid < 128) {
        #pragma unroll
        for (int g = 0; g < 32; ++g) s += ws[OFF_SY2 + g * 128 + tid];
    }
    red[tid] = (tid < 128) ? s * s : 0.f;
    if (tid < 32) {
        syn[tid] = ws[OFF_YN2 + tid];
        smx[tid] = ws[OFF_MX2 + tid];
        sdg[tid] = reinterpret_cast<const double*>(ws + OFF_DG2)[tid];
    }
    __syncthreads();
    for (int off = 128; off > 0; off >>= 1) {
        if (tid < off) red[tid] += red[tid + off];
        __syncthreads();
    }
    if (tid < 16) {
        for (int off = 16; off > 0; off >>= 1) {
            if (tid < off) {
                syn[tid] += syn[tid + off];
                sdg[tid] += sdg[tid + off];
                smx[tid]  = fmaxf(smx[tid], smx[tid + off]);
            }
        }
    }
    __syncthreads();
    const float  ss2   = red[0];
    const float  sumyn = syn[0];
    const double dsum  = sdg[0];
    const float  dgmax = smx[0];

    const float bound = 5.f + ss2 / (float)N_ROWS - sumyn + 10.f * dgmax;
    if (bound < -1.0e4f) {
        if (tid == 0) {
            outf[3 * NH]     = 0.0f;                              // nce_loss
            outf[3 * NH + 1] = (float)(-dsum / (double)N_ROWS);   // diagonal_loss
        }
        return;
    }

    // ---- exact fallback (unreachable for Gaussian benchmark data) ----
    __shared__ double snce[256];
    const float* X = outf;            // bi_enc
    const float* Y = outf + 2 * NH;   // bi_dec
    double nce = 0.0;
    for (int i = tid; i < N_ROWS; i += 256) {
        const float* xi = X + i * HDIM;
        float xn = 0.f;
        for (int h = 0; h < HDIM; ++h) xn += xi[h] * xi[h];
        double rowsum = 0.0;
        for (int j = 0; j < N_ROWS; ++j) {
            const float* yj = Y + j * HDIM;
            float yn = 0.f, xy = 0.f;
            for (int h = 0; h < HDIM; ++h) { yn += yj[h] * yj[h]; xy += xi[h] * yj[h]; }
            rowsum += (double)fmaxf(xn + yn - 2.f * xy, 0.f);
        }
        const float* yi = Y + i * HDIM;
        float yn = 0.f, xy = 0.f;
        for (int h = 0; h < HDIM; ++h) { yn += yi[h] * yi[h]; xy += xi[h] * yi[h]; }
        const float diag = fmaxf(xn + yn - 2.f * xy, 0.f);
        const double rl = 5.0 - rowsum + 10.0 * (double)diag;
        nce += (rl > 0.0) ? rl : 0.0;
    }
    snce[tid] = nce;
    __syncthreads();
    for (int off = 128; off > 0; off >>= 1) {
        if (tid < off) snce[tid] += snce[tid + off];
        __syncthreads();
    }
    if (tid == 0) {
        outf[3 * NH]     = (float)snce[0];
        outf[3 * NH + 1] = (float)(-dsum / (double)N_ROWS);
    }
}

extern "C" void kernel_launch(void* const* d_in, const int* in_sizes, int n_in,
                              void* d_out, int out_size, void* d_ws, size_t ws_size,
                              hipStream_t stream) {
    const float4* enc = (const float4*)d_in[0];   // [16384, 2, 128] fp32
    const float4* dec = (const float4*)d_in[1];   // [16384, 2, 128] fp32
    float* out = (float*)d_out;                   // 3*NH + 2 floats
    float* ws  = (float*)d_ws;

    k1_stream<<<B1, 256, 0, stream>>>(enc, dec, out, ws);
    k2_fold<<<32, 256, 0, stream>>>(ws);
    k3_finalize<<<1, 256, 0, stream>>>(ws, out);
}

// Round 5
// 87.445 us; speedup vs baseline: 1.9436x; 1.0246x over previous
//
#include <hip/hip_runtime.h>
#include <math.h>

// Problem constants (reference: N=16384, D=2, H=128, fp32)
#define N_ROWS 16384
#define HDIM   128
#define NH     (N_ROWS * HDIM)   // 2097152 floats per [N,H] output
#define NH4    (NH / 4)          // 524288 float4
#define B1     512               // k1 blocks: 512*256 threads, 4 float4 each

// Workspace layout (float offsets). Written before read; no atomics, no init.
#define OFF_SY1 0                      // 512*128 : per-block column sums of bi_dec
#define OFF_YN1 65536                  // 512     : per-block sum ||y||^2
#define OFF_DG1 66048                  // 512     : per-block sum (x-y)^2
#define OFF_MX1 66560                  // 512     : per-block max row diag

// K1: streaming pass. bi[i][h] = in[i*256+h] + in[i*256+128+h].
// float4 index v: row = v>>5, h4 = v&31; input float4 addr = 2v-h4 (+32 dir1).
// Grid-stride is a multiple of 32 so h4 is fixed per thread; lanes 0..31 of
// each half-wave hold one full row per iteration -> width-32 butterfly gives
// the row diag. No atomics: per-block partials via plain coalesced stores
// (r3 post-mortem: the 70us was the contended-atomic tail, not this loop).
__global__ __launch_bounds__(256) void k1_stream(
    const float4* __restrict__ enc, const float4* __restrict__ dec,
    float* __restrict__ outf, float* __restrict__ ws)
{
    float4* out4 = reinterpret_cast<float4*>(outf);
    const int tid  = threadIdx.x;
    const int b    = blockIdx.x;
    const int gid0 = b * 256 + tid;
    const int stride = B1 * 256;          // multiple of 32 -> h4 fixed
    const int h4 = tid & 31;

    float4 asy = make_float4(0.f, 0.f, 0.f, 0.f);
    float ayn = 0.f, adg = 0.f, dgmx = 0.f;

    for (int v = gid0; v < NH4; v += stride) {   // 4 iterations
        const int base = 2 * v - h4;
        float4 e0 = enc[base];
        float4 e1 = enc[base + 32];
        float4 d0 = dec[base];
        float4 d1 = dec[base + 32];
        float4 x = make_float4(e0.x + e1.x, e0.y + e1.y, e0.z + e1.z, e0.w + e1.w);
        float4 y = make_float4(d0.x + d1.x, d0.y + d1.y, d0.z + d1.z, d0.w + d1.w);
        out4[v]           = x;   // output 0: bi_enc
        out4[NH4 + v]     = x;   // output 1: bi_enc (duplicate)
        out4[2 * NH4 + v] = y;   // output 2: bi_dec

        asy.x += y.x; asy.y += y.y; asy.z += y.z; asy.w += y.w;
        ayn += y.x * y.x + y.y * y.y + y.z * y.z + y.w * y.w;

        float fx = x.x - y.x, fy = x.y - y.y, fz = x.z - y.z, fw = x.w - y.w;
        float dg = fx * fx + fy * fy + fz * fz + fw * fw;
        adg += dg;
        #pragma unroll
        for (int m = 16; m > 0; m >>= 1) dg += __shfl_xor(dg, m, 32);  // full-row diag
        dgmx = fmaxf(dgmx, dg);
    }

    __shared__ float4 ssy[256];
    __shared__ float s_yn[256], s_dg[256], s_mx[256];
    ssy[tid] = asy; s_yn[tid] = ayn; s_dg[tid] = adg; s_mx[tid] = dgmx;
    __syncthreads();
    for (int off = 128; off > 0; off >>= 1) {
        if (tid < off) {
            s_yn[tid] += s_yn[tid + off];
            s_dg[tid] += s_dg[tid + off];
            s_mx[tid]  = fmaxf(s_mx[tid], s_mx[tid + off]);
        }
        __syncthreads();
    }
    if (tid < 32) {   // column partial: thread t owns float4-columns t
        float4 t = ssy[tid];
        #pragma unroll
        for (int k = 1; k < 8; ++k) {
            float4 u = ssy[tid + 32 * k];
            t.x += u.x; t.y += u.y; t.z += u.z; t.w += u.w;
        }
        reinterpret_cast<float4*>(ws + OFF_SY1)[b * 32 + tid] = t;
    }
    if (tid == 0) {
        ws[OFF_YN1 + b] = s_yn[0];
        ws[OFF_DG1 + b] = s_dg[0];
        ws[OFF_MX1 + b] = s_mx[0];
    }
}

// K2 (1 block): full finalize. Partials are only 256 KB + 6 KB, read as
// independent coalesced float4 loads (MLP-pipelined; NOT round-2's serial
// dependent-scalar scan).
// row_loss_i = 5 - sum_j dist_cl[i,j] + 10*dg_i, dist_cl >= dist_exact, so
// row_loss_i <= 5 - N*xn_i - sumyn + 2*sqrt(xn_i*||S_y||^2) + 10*dg_i
//            <= 5 + ||S_y||^2/N - sumyn + 10*max_dg   (max over xn, C-S).
// Here ~ 5 + 256 - 4.2e6 + ~1e4 << 0  ->  every clamped row_loss is 0 exactly.
// Exact O(N^2 H) fallback kept for full generality (never taken).
__global__ __launch_bounds__(256) void k2_finalize(
    const float* __restrict__ ws, float* __restrict__ outf)
{
    const int tid = threadIdx.x;
    const float4* SY1 = reinterpret_cast<const float4*>(ws + OFF_SY1);

    // --- S_y: 256 threads = 32 col4-groups x 8 row-slices; 64 float4 each ---
    const int col4 = tid & 31, r = tid >> 5;
    float4 a = make_float4(0.f, 0.f, 0.f, 0.f);
    #pragma unroll 8
    for (int j = 0; j < 64; ++j) {
        float4 u = SY1[(r * 64 + j) * 32 + col4];
        a.x += u.x; a.y += u.y; a.z += u.z; a.w += u.w;
    }

    // --- scalars: 512 each of yn / dg / mx; thread reads 2 of each ---
    float yn = ws[OFF_YN1 + tid] + ws[OFF_YN1 + 256 + tid];
    double dgd = (double)ws[OFF_DG1 + tid] + (double)ws[OFF_DG1 + 256 + tid];
    float mx = fmaxf(ws[OFF_MX1 + tid], ws[OFF_MX1 + 256 + tid]);

    __shared__ float4 sred[256];
    __shared__ float s_yn[256], s_mx[256];
    __shared__ double s_dg[256];
    sred[tid] = a; s_yn[tid] = yn; s_mx[tid] = mx; s_dg[tid] = dgd;
    __syncthreads();
    for (int off = 128; off >= 32; off >>= 1) {
        if (tid < off) {
            float4 u = sred[tid + off];
            sred[tid].x += u.x; sred[tid].y += u.y;
            sred[tid].z += u.z; sred[tid].w += u.w;
        }
        __syncthreads();
    }
    for (int off = 128; off > 0; off >>= 1) {
        if (tid < off) {
            s_yn[tid] += s_yn[tid + off];
            s_dg[tid] += s_dg[tid + off];
            s_mx[tid]  = fmaxf(s_mx[tid], s_mx[tid + off]);
        }
        __syncthreads();
    }

    // sred[0..31] = S_y as float4. ||S_y||^2 via LDS reduce.
    __shared__ float sy[128];
    __shared__ float red[256];
    if (tid < 32) reinterpret_cast<float4*>(sy)[tid] = sred[tid];
    __syncthreads();
    red[tid] = (tid < 128) ? sy[tid] * sy[tid] : 0.f;
    __syncthreads();
    for (int off = 128; off > 0; off >>= 1) {
        if (tid < off) red[tid] += red[tid + off];
        __syncthreads();
    }

    const float  ss2   = red[0];
    const float  sumyn = s_yn[0];
    const double dsum  = s_dg[0];
    const float  dgmax = s_mx[0];

    const float bound = 5.f + ss2 / (float)N_ROWS - sumyn + 10.f * dgmax;
    if (bound < -1.0e4f) {
        if (tid == 0) {
            outf[3 * NH]     = 0.0f;                              // nce_loss
            outf[3 * NH + 1] = (float)(-dsum / (double)N_ROWS);   // diagonal_loss
        }
        return;
    }

    // ---- exact fallback (unreachable for Gaussian benchmark data) ----
    __shared__ double snce[256];
    const float* X = outf;            // bi_enc
    const float* Y = outf + 2 * NH;   // bi_dec
    double nce = 0.0;
    for (int i = tid; i < N_ROWS; i += 256) {
        const float* xi = X + i * HDIM;
        float xn = 0.f;
        for (int h = 0; h < HDIM; ++h) xn += xi[h] * xi[h];
        double rowsum = 0.0;
        for (int j = 0; j < N_ROWS; ++j) {
            const float* yj = Y + j * HDIM;
            float ynn = 0.f, xy = 0.f;
            for (int h = 0; h < HDIM; ++h) { ynn += yj[h] * yj[h]; xy += xi[h] * yj[h]; }
            rowsum += (double)fmaxf(xn + ynn - 2.f * xy, 0.f);
        }
        const float* yi = Y + i * HDIM;
        float ynn = 0.f, xy = 0.f;
        for (int h = 0; h < HDIM; ++h) { ynn += yi[h] * yi[h]; xy += xi[h] * yi[h]; }
        const float diag = fmaxf(xn + ynn - 2.f * xy, 0.f);
        const double rl = 5.0 - rowsum + 10.0 * (double)diag;
        nce += (rl > 0.0) ? rl : 0.0;
    }
    snce[tid] = nce;
    __syncthreads();
    for (int off = 128; off > 0; off >>= 1) {
        if (tid < off) snce[tid] += snce[tid + off];
        __syncthreads();
    }
    if (tid == 0) {
        outf[3 * NH]     = (float)snce[0];
        outf[3 * NH + 1] = (float)(-dsum / (double)N_ROWS);
    }
}

extern "C" void kernel_launch(void* const* d_in, const int* in_sizes, int n_in,
                              void* d_out, int out_size, void* d_ws, size_t ws_size,
                              hipStream_t stream) {
    const float4* enc = (const float4*)d_in[0];   // [16384, 2, 128] fp32
    const float4* dec = (const float4*)d_in[1];   // [16384, 2, 128] fp32
    float* out = (float*)d_out;                   // 3*NH + 2 floats
    float* ws  = (float*)d_ws;

    k1_stream<<<B1, 256, 0, stream>>>(enc, dec, out, ws);
    k2_finalize<<<1, 256, 0, stream>>>(ws, out);
}